// Round 3
// baseline (1472.697 us; speedup 1.0000x reference)
//
#include <hip/hip_runtime.h>
#include <math.h>

#define L_  50
#define T_  100
#define D_  128
#define NEG_INF_ -9000000000000000.0f

__device__ __forceinline__ float wred_sum(float v) {
#pragma unroll
    for (int o = 32; o > 0; o >>= 1) v += __shfl_xor(v, o, 64);
    return v;
}
__device__ __forceinline__ float wred_max(float v) {
#pragma unroll
    for (int o = 32; o > 0; o >>= 1) v = fmaxf(v, __shfl_xor(v, o, 64));
    return v;
}
__device__ __forceinline__ float rdlane(float v, int l) {
    return __uint_as_float(__builtin_amdgcn_readlane(__float_as_uint(v), l));
}

// h[l][g] = op( sum_d x[l][d] * W[d][g] (+ bias[g]) )
// 256 threads: lq = tid&15 (rows lq, lq+16, lq+32 [, lq+48 if lq<2]),
// g0 = (tid>>4)*8 (8 consecutive output cols). W streamed from global
// (L1/L2-resident; 16 lanes share each address -> broadcast). No barriers.
// Row stride 132 floats: bank start = (4*row + col) % 32 -> max 2-way (free).
template <int MODE>  // 0: raw store, 1: tanh(acc + bias)
__device__ __forceinline__ void gemm50(const float* __restrict__ W,
                                       const float* __restrict__ bias,
                                       const float (&xin)[50][132],
                                       float (&hout)[50][132], int tid) {
    const int lq = tid & 15;
    const int g0 = (tid >> 4) << 3;
    const int nl = (lq < 2) ? 4 : 3;
    float acc[4][8];
#pragma unroll
    for (int i = 0; i < 4; ++i)
#pragma unroll
        for (int j = 0; j < 8; ++j) acc[i][j] = 0.f;

    const float* Wg = W + g0;
#pragma unroll 2
    for (int d0 = 0; d0 < 128; d0 += 4) {
        float4 wv[4][2];
#pragma unroll
        for (int k = 0; k < 4; ++k) {
            const float* wr = Wg + (size_t)(d0 + k) * 128;
            wv[k][0] = *(const float4*)wr;
            wv[k][1] = *(const float4*)(wr + 4);
        }
        float4 xq[4];
#pragma unroll
        for (int il = 0; il < 4; ++il)
            if (il < nl) xq[il] = *(const float4*)&xin[lq + (il << 4)][d0];
#pragma unroll
        for (int k = 0; k < 4; ++k) {
            const float4 wa = wv[k][0], wb = wv[k][1];
#pragma unroll
            for (int il = 0; il < 4; ++il)
                if (il < nl) {
                    const float xs = (k == 0) ? xq[il].x
                                   : (k == 1) ? xq[il].y
                                   : (k == 2) ? xq[il].z
                                              : xq[il].w;
                    acc[il][0] = fmaf(xs, wa.x, acc[il][0]);
                    acc[il][1] = fmaf(xs, wa.y, acc[il][1]);
                    acc[il][2] = fmaf(xs, wa.z, acc[il][2]);
                    acc[il][3] = fmaf(xs, wa.w, acc[il][3]);
                    acc[il][4] = fmaf(xs, wb.x, acc[il][4]);
                    acc[il][5] = fmaf(xs, wb.y, acc[il][5]);
                    acc[il][6] = fmaf(xs, wb.z, acc[il][6]);
                    acc[il][7] = fmaf(xs, wb.w, acc[il][7]);
                }
        }
    }

    float4 ba, bb;
    if (MODE == 1) {
        ba = *(const float4*)&bias[g0];
        bb = *(const float4*)&bias[g0 + 4];
    }
#pragma unroll
    for (int il = 0; il < 4; ++il)
        if (il < nl) {
            const int l = lq + (il << 4);
            if (MODE == 1) {
                hout[l][g0 + 0] = tanhf(acc[il][0] + ba.x);
                hout[l][g0 + 1] = tanhf(acc[il][1] + ba.y);
                hout[l][g0 + 2] = tanhf(acc[il][2] + ba.z);
                hout[l][g0 + 3] = tanhf(acc[il][3] + ba.w);
                hout[l][g0 + 4] = tanhf(acc[il][4] + bb.x);
                hout[l][g0 + 5] = tanhf(acc[il][5] + bb.y);
                hout[l][g0 + 6] = tanhf(acc[il][6] + bb.z);
                hout[l][g0 + 7] = tanhf(acc[il][7] + bb.w);
            } else {
                *(float4*)&hout[l][g0] =
                    make_float4(acc[il][0], acc[il][1], acc[il][2], acc[il][3]);
                *(float4*)&hout[l][g0 + 4] =
                    make_float4(acc[il][4], acc[il][5], acc[il][6], acc[il][7]);
            }
        }
}

extern "C" __global__ void __launch_bounds__(256, 3) magnn_fused(
    const int* __restrict__ iseq, const int* __restrict__ uids,
    const int* __restrict__ itp, const int* __restrict__ A,
    const float* __restrict__ item_emb, const float* __restrict__ user_emb,
    const float* __restrict__ W2t, const float* __restrict__ b2t,
    const float* __restrict__ W_att, const float* __restrict__ a_att,
    const float* __restrict__ W_out, const float* __restrict__ a_out,
    const float* __restrict__ att1_W, const float* __restrict__ att1_b,
    const float* __restrict__ att2_W, const float* __restrict__ att2_b,
    const float* __restrict__ user_com, float* __restrict__ out) {
    // LDS: 2*50*132*4 + 384*4 = 54336 B <= 54613 -> 3 blocks/CU.
    // Stride 132 floats => bank start (4*row+col)%32: gemm's 16-row column
    // reads are 2-way (free) instead of 16-way at stride 128.
    __shared__ __align__(16) float x[50][132];
    __shared__ __align__(16) float h[50][132];
    __shared__ __align__(16) float scratch[384];
    // phase-local aliases (lifetimes separated by barriers):
    float* f1s = scratch;          // [64]  GAT
    float* f2s = scratch + 64;     // [64]  GAT
    float* cat = scratch;          // [256] matrix_z -> fusion
    float* fpart = scratch + 256;  // [128] fusion partials
    float* vvec = scratch;         // [128] fusion result (cat dead after barrier)
    // attn (50 x float4) lives in h's pad columns: &h[l][128]

    const int tid = threadIdx.x;
    const int b = blockIdx.x;
    const int w = tid >> 6, lane = tid & 63;

    // ---- gather item embeddings into x ----
    {
        const int* isq = iseq + b * L_;
        for (int i = tid; i < L_ * 32; i += 256) {
            const int l = i >> 5, c4 = (i & 31) << 2;
            const int it = isq[l];
            *(float4*)&x[l][c4] = *(const float4*)&item_emb[(size_t)it * D_ + c4];
        }
    }
    __syncthreads();

    // ---- s[d] = sum_l item_embs[l][d], kept in a register of thread d<128 ----
    float sval = 0.f;
    if (tid < 128) {
#pragma unroll 5
        for (int l = 0; l < L_; ++l) sval += x[l][tid];
    }

    // ---- 2 GAT layers: x = elu(softmax_adj(tanh(f1_i+f2_j)) @ (x@W)) ----
#pragma unroll 1
    for (int layer = 0; layer < 2; ++layer) {
        const float* Wl = layer ? W_out : W_att;
        const float* al = layer ? a_out : a_att;
        gemm50<0>(Wl, nullptr, x, h, tid);
        __syncthreads();
        // f1[l] = h[l,:]·a[:128], f2[l] = h[l,:]·a[128:]
        {
            const float a1l = al[lane], a1h = al[lane + 64];
            const float a2l = al[128 + lane], a2h = al[192 + lane];
            for (int l = w; l < L_; l += 4) {
                const float h0 = h[l][lane], h1 = h[l][lane + 64];
                const float r1 = wred_sum(fmaf(h0, a1l, h1 * a1h));
                const float r2 = wred_sum(fmaf(h0, a2l, h1 * a2h));
                if (lane == 0) { f1s[l] = r1; f2s[l] = r2; }
            }
        }
        __syncthreads();
        // masked softmax rows + h' = att @ h, 4 rows per wave
        {
            const int* Ab = A + (size_t)b * (L_ * L_);
            const float f2v = (lane < L_) ? f2s[lane] : 0.f;
            for (int k0 = 0; k0 < 13; k0 += 4) {
                float attv[4];
                int lr[4];
                bool vr[4];
#pragma unroll
                for (int r = 0; r < 4; ++r) {
                    const int k = k0 + r;
                    const int l = w + 4 * k;
                    lr[r] = l;
                    vr[r] = (k < 13) && (l < L_);
                    attv[r] = 0.f;
                    if (vr[r]) {
                        const float f1l = f1s[l];
                        const int adj = (lane < L_) ? Ab[l * L_ + lane] : 0;
                        const float e = tanhf(f1l + f2v);
                        const float val =
                            (lane < L_) ? (adj > 0 ? e : NEG_INF_) : -INFINITY;
                        const float m = wred_max(val);
                        const float p = __expf(val - m);
                        const float s = wred_sum(p);
                        attv[r] = p / s;
                    }
                }
                float ac0[4] = {0.f, 0.f, 0.f, 0.f}, ac1[4] = {0.f, 0.f, 0.f, 0.f};
#pragma unroll
                for (int j = 0; j < L_; ++j) {
                    const float h0 = h[j][lane], h1 = h[j][lane + 64];
#pragma unroll
                    for (int r = 0; r < 4; ++r) {
                        const float aj = rdlane(attv[r], j);
                        ac0[r] = fmaf(aj, h0, ac0[r]);
                        ac1[r] = fmaf(aj, h1, ac1[r]);
                    }
                }
#pragma unroll
                for (int r = 0; r < 4; ++r)
                    if (vr[r]) {
                        const float e0 = ac0[r], e1 = ac1[r];
                        x[lr[r]][lane] = e0 > 0.f ? e0 : expm1f(e0);
                        x[lr[r]][lane + 64] = e1 > 0.f ? e1 : expm1f(e1);
                    }
            }
        }
        __syncthreads();
    }

    // ---- m1 = tanh(x @ att1_W + att1_b) -> h ----
    gemm50<1>(att1_W, att1_b, x, h, tid);
    __syncthreads();

    // ---- m2 = m1 @ att2_W + att2_b; attn = softmax over H=4 -> h[l][128..131] ----
    {
        const float4 awl = *(const float4*)&att2_W[lane * 4];
        const float4 awh = *(const float4*)&att2_W[(lane + 64) * 4];
        const float bb0 = att2_b[0], bb1 = att2_b[1], bb2 = att2_b[2], bb3 = att2_b[3];
        for (int l = w; l < L_; l += 4) {
            const float q0 = h[l][lane], q1 = h[l][lane + 64];
            float m0 = wred_sum(fmaf(q0, awl.x, q1 * awh.x)) + bb0;
            float m1 = wred_sum(fmaf(q0, awl.y, q1 * awh.y)) + bb1;
            float m2 = wred_sum(fmaf(q0, awl.z, q1 * awh.z)) + bb2;
            float m3 = wred_sum(fmaf(q0, awl.w, q1 * awh.w)) + bb3;
            const float mx = fmaxf(fmaxf(m0, m1), fmaxf(m2, m3));
            const float e0 = __expf(m0 - mx), e1 = __expf(m1 - mx);
            const float e2 = __expf(m2 - mx), e3 = __expf(m3 - mx);
            const float inv = 1.f / (e0 + e1 + e2 + e3);
            if (lane == 0)
                *(float4*)&h[l][128] =
                    make_float4(e0 * inv, e1 * inv, e2 * inv, e3 * inv);
        }
    }
    __syncthreads();

    // ---- matrix_z / attention_embs -> cat[0:128]; user_emb -> cat[128:256] ----
    if (tid < 128) {
        const int d = tid;
        float z0 = 0.f, z1 = 0.f, z2 = 0.f, z3 = 0.f;
        for (int l = 0; l < L_; ++l) {
            const float xv = x[l][d];
            const float4 at = *(const float4*)&h[l][128];  // broadcast read
            z0 = fmaf(xv, at.x, z0);
            z1 = fmaf(xv, at.y, z1);
            z2 = fmaf(xv, at.z, z2);
            z3 = fmaf(xv, at.w, z3);
        }
        cat[d] = 0.25f * (tanhf(z0) + tanhf(z1) + tanhf(z2) + tanhf(z3));
    } else {
        const int d = tid - 128;
        const int uid = uids[b];
        cat[tid] = user_emb[(size_t)uid * D_ + d];
    }
    __syncthreads();

    // ---- fusion = cat @ user_com; v = fusion + s ----
    {
        const int g = tid & 127, hf = tid >> 7;
        float acc = 0.f;
        const float* ucb = user_com + hf * 128 * 128 + g;
        const float* cc = &cat[hf * 128];
#pragma unroll 4
        for (int k = 0; k < 128; ++k) acc = fmaf(cc[k], ucb[(size_t)k * 128], acc);
        if (hf) fpart[g] = acc;  // scratch[256:384] -- does not alias cat
        __syncthreads();
        if (!hf) vvec[g] = acc + fpart[g] + sval;  // overwrites cat[0:128] (dead)
    }
    __syncthreads();

    // ---- out[b,t] = w2[t]·v + b2[t] ----
    {
        const float vl = vvec[lane], vh = vvec[lane + 64];
        const int* itpb = itp + b * T_;
        for (int t = w; t < T_; t += 4) {
            const int item = itpb[t];
            const float* w2r = W2t + (size_t)item * D_;
            float r = fmaf(w2r[lane], vl, w2r[lane + 64] * vh);
            r = wred_sum(r);
            if (lane == 0) out[b * T_ + t] = r + b2t[item];
        }
    }
}

extern "C" void kernel_launch(void* const* d_in, const int* in_sizes, int n_in,
                              void* d_out, int out_size, void* d_ws, size_t ws_size,
                              hipStream_t stream) {
    const int* iseq = (const int*)d_in[0];
    const int* uids = (const int*)d_in[1];
    const int* itp = (const int*)d_in[2];
    const int* A = (const int*)d_in[3];
    const float* item_emb = (const float*)d_in[4];
    const float* user_emb = (const float*)d_in[5];
    const float* W2t = (const float*)d_in[6];
    const float* b2t = (const float*)d_in[7];
    const float* W_att = (const float*)d_in[8];
    const float* a_att = (const float*)d_in[9];
    const float* W_out = (const float*)d_in[10];
    const float* a_out = (const float*)d_in[11];
    const float* att1_W = (const float*)d_in[12];
    const float* att1_b = (const float*)d_in[13];
    const float* att2_W = (const float*)d_in[14];
    const float* att2_b = (const float*)d_in[15];
    const float* user_com = (const float*)d_in[16];
    float* out = (float*)d_out;

    const int B = in_sizes[1];  // user_ids is (B,)
    magnn_fused<<<dim3(B), dim3(256), 0, stream>>>(
        iseq, uids, itp, A, item_emb, user_emb, W2t, b2t, W_att, a_att, W_out,
        a_out, att1_W, att1_b, att2_W, att2_b, user_com, out);
}

// Round 4
// 1181.086 us; speedup vs baseline: 1.2469x; 1.2469x over previous
//
#include <hip/hip_runtime.h>
#include <math.h>

#define L_  50
#define T_  100
#define D_  128
#define NEG_INF_ -9000000000000000.0f

using bf16x8 = __attribute__((ext_vector_type(8))) short;
using f32x4 = __attribute__((ext_vector_type(4))) float;

__device__ __forceinline__ float wred_sum(float v) {
#pragma unroll
    for (int o = 32; o > 0; o >>= 1) v += __shfl_xor(v, o, 64);
    return v;
}
__device__ __forceinline__ float wred_max(float v) {
#pragma unroll
    for (int o = 32; o > 0; o >>= 1) v = fmaxf(v, __shfl_xor(v, o, 64));
    return v;
}
__device__ __forceinline__ float rdlane(float v, int l) {
    return __uint_as_float(__builtin_amdgcn_readlane(__float_as_uint(v), l));
}
__device__ __forceinline__ short f2bf(float f) {  // RNE fp32 -> bf16 bits
    unsigned u = __float_as_uint(f);
    return (short)((u + 0x7fffu + ((u >> 16) & 1u)) >> 16);
}

// ---------------- pre-pass: W (128x128 fp32) -> bf16 in MFMA B-frag order ---
// Wb[mat][((kt*8+nt)*64 + lane)*8 + j] = bf16( W[kt*32 + (lane>>4)*8 + j][nt*16 + (lane&15)] )
// (B operand of mfma_f32_16x16x32_bf16: lane holds B[k = quad*8+j][n = lane&15])
extern "C" __global__ void __launch_bounds__(256) magnn_preswizzle(
    const float* __restrict__ W0, const float* __restrict__ W1,
    const float* __restrict__ W2, unsigned short* __restrict__ out) {
    const int t = blockIdx.x * 256 + threadIdx.x;  // 0..6143, 8 elems each
    const int mat = t >> 11;
    const int chunk = t & 2047;
    const int ktnt = chunk >> 6, lane = chunk & 63;
    const int kt = ktnt >> 3, nt = ktnt & 7;
    const int k0 = kt * 32 + (lane >> 4) * 8;
    const int n = nt * 16 + (lane & 15);
    const float* Ws = (mat == 0) ? W0 : (mat == 1) ? W1 : W2;
    bf16x8 v;
#pragma unroll
    for (int j = 0; j < 8; ++j) v[j] = f2bf(Ws[(size_t)(k0 + j) * 128 + n]);
    *(bf16x8*)(out + (size_t)t * 8) = v;
}

// ---------------- MFMA gemm: hout = op( xin(50x128) @ W(128x128) ) ------------
// Per wave: 16-row stripe (wave w -> rows w*16..w*16+15), 8 N-tiles, K in 4 steps.
// A-frag from LDS fp32 (cvt to bf16), B-frag one dwordx4 from pre-swizzled Wb.
template <int MODE>  // 0: raw store, 1: tanh(acc + bias)
__device__ __forceinline__ void gemm50_mfma(const unsigned short* __restrict__ Wb,
                                            const float* __restrict__ bias,
                                            const float (&xin)[50][132],
                                            float (&hout)[50][132], int w, int lane) {
    const int n = lane & 15, quad = lane >> 4;
    const int mrd = w * 16 + n;
    const int mr = (mrd < 50) ? mrd : 49;  // clamp pad rows (results discarded)
    f32x4 acc[8];
#pragma unroll
    for (int nt = 0; nt < 8; ++nt) acc[nt] = (f32x4){0.f, 0.f, 0.f, 0.f};

#pragma unroll
    for (int kt = 0; kt < 4; ++kt) {
        const float* ap = &xin[mr][kt * 32 + quad * 8];
        const float4 a0 = *(const float4*)ap;
        const float4 a1 = *(const float4*)(ap + 4);
        bf16x8 af;
        af[0] = f2bf(a0.x); af[1] = f2bf(a0.y); af[2] = f2bf(a0.z); af[3] = f2bf(a0.w);
        af[4] = f2bf(a1.x); af[5] = f2bf(a1.y); af[6] = f2bf(a1.z); af[7] = f2bf(a1.w);
        const unsigned short* bp = Wb + (((kt * 8) * 64 + lane) << 3);
#pragma unroll
        for (int nt = 0; nt < 8; ++nt) {
            const bf16x8 bfr = *(const bf16x8*)(bp + (nt << 9));  // (nt*64)*8
            acc[nt] = __builtin_amdgcn_mfma_f32_16x16x32_bf16(af, bfr, acc[nt], 0, 0, 0);
        }
    }
    // C/D: col = lane&15, row(tile) = quad*4 + reg
    const int rbase = w * 16 + quad * 4;
#pragma unroll
    for (int nt = 0; nt < 8; ++nt) {
        const int col = nt * 16 + n;
        const float bv = (MODE == 1) ? bias[col] : 0.f;
#pragma unroll
        for (int reg = 0; reg < 4; ++reg) {
            const int row = rbase + reg;
            if (row < 50)
                hout[row][col] = (MODE == 1) ? tanhf(acc[nt][reg] + bv) : acc[nt][reg];
        }
    }
}

extern "C" __global__ void __launch_bounds__(256, 3) magnn_fused(
    const int* __restrict__ iseq, const int* __restrict__ uids,
    const int* __restrict__ itp, const int* __restrict__ A,
    const float* __restrict__ item_emb, const float* __restrict__ user_emb,
    const float* __restrict__ W2t, const float* __restrict__ b2t,
    const float* __restrict__ a_att, const float* __restrict__ a_out,
    const float* __restrict__ att1_b, const float* __restrict__ att2_W,
    const float* __restrict__ att2_b, const float* __restrict__ user_com,
    const unsigned short* __restrict__ Wb, float* __restrict__ out) {
    // LDS: 2*50*132*4 + 256*4 = 53824 B -> rounds to 54272 <= 54613 -> 3 blocks/CU
    __shared__ __align__(16) float x[50][132];
    __shared__ __align__(16) float h[50][132];
    __shared__ __align__(16) float scratch[256];
    float* f1s = scratch;        // [64]  GAT
    float* f2s = scratch + 64;   // [64]  GAT
    float* cat = scratch;        // [256] matrix_z -> fusion
    float* vvec = scratch;       // [128] fusion result (cat dead)
    float* fpart = &x[0][0];     // [128] fusion partials (x dead by then)
    // attn (50 x float4) lives in h's pad columns &h[l][128]

    const int tid = threadIdx.x;
    const int b = blockIdx.x;
    const int w = tid >> 6, lane = tid & 63;

    // ---- gather item embeddings into x ----
    {
        const int* isq = iseq + b * L_;
        for (int i = tid; i < L_ * 32; i += 256) {
            const int l = i >> 5, c4 = (i & 31) << 2;
            const int it = isq[l];
            *(float4*)&x[l][c4] = *(const float4*)&item_emb[(size_t)it * D_ + c4];
        }
    }
    __syncthreads();

    // ---- s[d] = sum_l item_embs[l][d] in a register of thread d<128 ----
    float sval = 0.f;
    if (tid < 128) {
#pragma unroll 5
        for (int l = 0; l < L_; ++l) sval += x[l][tid];
    }

    // ---- 2 GAT layers ----
#pragma unroll 1
    for (int layer = 0; layer < 2; ++layer) {
        const unsigned short* Wl = Wb + (layer ? 16384 : 0);
        const float* al = layer ? a_out : a_att;
        gemm50_mfma<0>(Wl, nullptr, x, h, w, lane);
        __syncthreads();
        // f1[l] = h[l,:]·a[:128], f2[l] = h[l,:]·a[128:]
        {
            const float a1l = al[lane], a1h = al[lane + 64];
            const float a2l = al[128 + lane], a2h = al[192 + lane];
            for (int l = w; l < L_; l += 4) {
                const float h0 = h[l][lane], h1 = h[l][lane + 64];
                const float r1 = wred_sum(fmaf(h0, a1l, h1 * a1h));
                const float r2 = wred_sum(fmaf(h0, a2l, h1 * a2h));
                if (lane == 0) { f1s[l] = r1; f2s[l] = r2; }
            }
        }
        __syncthreads();
        // masked softmax rows + h' = att @ h, 4 rows per wave
        {
            const int* Ab = A + (size_t)b * (L_ * L_);
            const float f2v = (lane < L_) ? f2s[lane] : 0.f;
            for (int k0 = 0; k0 < 13; k0 += 4) {
                float attv[4];
                int lr[4];
                bool vr[4];
#pragma unroll
                for (int r = 0; r < 4; ++r) {
                    const int k = k0 + r;
                    const int l = w + 4 * k;
                    lr[r] = l;
                    vr[r] = (k < 13) && (l < L_);
                    attv[r] = 0.f;
                    if (vr[r]) {
                        const float f1l = f1s[l];
                        const int adj = (lane < L_) ? Ab[l * L_ + lane] : 0;
                        const float e = tanhf(f1l + f2v);
                        const float val =
                            (lane < L_) ? (adj > 0 ? e : NEG_INF_) : -INFINITY;
                        const float m = wred_max(val);
                        const float p = __expf(val - m);
                        const float s = wred_sum(p);
                        attv[r] = p / s;
                    }
                }
                float ac0[4] = {0.f, 0.f, 0.f, 0.f}, ac1[4] = {0.f, 0.f, 0.f, 0.f};
#pragma unroll
                for (int j = 0; j < L_; ++j) {
                    const float h0 = h[j][lane], h1 = h[j][lane + 64];
#pragma unroll
                    for (int r = 0; r < 4; ++r) {
                        const float aj = rdlane(attv[r], j);
                        ac0[r] = fmaf(aj, h0, ac0[r]);
                        ac1[r] = fmaf(aj, h1, ac1[r]);
                    }
                }
#pragma unroll
                for (int r = 0; r < 4; ++r)
                    if (vr[r]) {
                        const float e0 = ac0[r], e1 = ac1[r];
                        x[lr[r]][lane] = e0 > 0.f ? e0 : expm1f(e0);
                        x[lr[r]][lane + 64] = e1 > 0.f ? e1 : expm1f(e1);
                    }
            }
        }
        __syncthreads();
    }

    // ---- m1 = tanh(x @ att1_W + att1_b) -> h ----
    gemm50_mfma<1>(Wb + 32768, att1_b, x, h, w, lane);
    __syncthreads();

    // ---- m2 = m1 @ att2_W + att2_b; attn = softmax over H=4 -> h[l][128..131] ----
    {
        const float4 awl = *(const float4*)&att2_W[lane * 4];
        const float4 awh = *(const float4*)&att2_W[(lane + 64) * 4];
        const float bb0 = att2_b[0], bb1 = att2_b[1], bb2 = att2_b[2], bb3 = att2_b[3];
        for (int l = w; l < L_; l += 4) {
            const float q0 = h[l][lane], q1 = h[l][lane + 64];
            float m0 = wred_sum(fmaf(q0, awl.x, q1 * awh.x)) + bb0;
            float m1 = wred_sum(fmaf(q0, awl.y, q1 * awh.y)) + bb1;
            float m2 = wred_sum(fmaf(q0, awl.z, q1 * awh.z)) + bb2;
            float m3 = wred_sum(fmaf(q0, awl.w, q1 * awh.w)) + bb3;
            const float mx = fmaxf(fmaxf(m0, m1), fmaxf(m2, m3));
            const float e0 = __expf(m0 - mx), e1 = __expf(m1 - mx);
            const float e2 = __expf(m2 - mx), e3 = __expf(m3 - mx);
            const float inv = 1.f / (e0 + e1 + e2 + e3);
            if (lane == 0)
                *(float4*)&h[l][128] =
                    make_float4(e0 * inv, e1 * inv, e2 * inv, e3 * inv);
        }
    }
    __syncthreads();

    // ---- matrix_z / attention_embs -> cat[0:128]; user_emb -> cat[128:256] ----
    if (tid < 128) {
        const int d = tid;
        float z0 = 0.f, z1 = 0.f, z2 = 0.f, z3 = 0.f;
        for (int l = 0; l < L_; ++l) {
            const float xv = x[l][d];
            const float4 at = *(const float4*)&h[l][128];
            z0 = fmaf(xv, at.x, z0);
            z1 = fmaf(xv, at.y, z1);
            z2 = fmaf(xv, at.z, z2);
            z3 = fmaf(xv, at.w, z3);
        }
        const float zv = 0.25f * (tanhf(z0) + tanhf(z1) + tanhf(z2) + tanhf(z3));
        __syncthreads();              // everyone past matrix_z reads before cat write
        cat[d] = zv;
    } else {
        const int d = tid - 128;
        const int uid = uids[b];
        const float ue = user_emb[(size_t)uid * D_ + d];
        __syncthreads();
        cat[tid] = ue;
    }
    __syncthreads();

    // ---- fusion = cat @ user_com; v = fusion + s ----
    {
        const int g = tid & 127, hf = tid >> 7;
        float acc = 0.f;
        const float* ucb = user_com + hf * 128 * 128 + g;
        const float* cc = &cat[hf * 128];
#pragma unroll 4
        for (int k = 0; k < 128; ++k) acc = fmaf(cc[k], ucb[(size_t)k * 128], acc);
        if (hf) fpart[g] = acc;  // x[0][0..127]: x fully dead here
        __syncthreads();
        if (!hf) vvec[g] = acc + fpart[g] + sval;
    }
    __syncthreads();

    // ---- out[b,t] = w2[t]·v + b2[t] ----
    {
        const float vl = vvec[lane], vh = vvec[lane + 64];
        const int* itpb = itp + b * T_;
        for (int t = w; t < T_; t += 4) {
            const int item = itpb[t];
            const float* w2r = W2t + (size_t)item * D_;
            float r = fmaf(w2r[lane], vl, w2r[lane + 64] * vh);
            r = wred_sum(r);
            if (lane == 0) out[b * T_ + t] = r + b2t[item];
        }
    }
}

extern "C" void kernel_launch(void* const* d_in, const int* in_sizes, int n_in,
                              void* d_out, int out_size, void* d_ws, size_t ws_size,
                              hipStream_t stream) {
    const int* iseq = (const int*)d_in[0];
    const int* uids = (const int*)d_in[1];
    const int* itp = (const int*)d_in[2];
    const int* A = (const int*)d_in[3];
    const float* item_emb = (const float*)d_in[4];
    const float* user_emb = (const float*)d_in[5];
    const float* W2t = (const float*)d_in[6];
    const float* b2t = (const float*)d_in[7];
    const float* W_att = (const float*)d_in[8];
    const float* a_att = (const float*)d_in[9];
    const float* W_out = (const float*)d_in[10];
    const float* a_out = (const float*)d_in[11];
    const float* att1_W = (const float*)d_in[12];
    const float* att1_b = (const float*)d_in[13];
    const float* att2_W = (const float*)d_in[14];
    const float* att2_b = (const float*)d_in[15];
    const float* user_com = (const float*)d_in[16];
    float* out = (float*)d_out;
    unsigned short* Wb = (unsigned short*)d_ws;  // 3 * 16384 bf16 = 96 KB

    magnn_preswizzle<<<dim3(24), dim3(256), 0, stream>>>(W_att, W_out, att1_W, Wb);

    const int B = in_sizes[1];  // user_ids is (B,)
    magnn_fused<<<dim3(B), dim3(256), 0, stream>>>(
        iseq, uids, itp, A, item_emb, user_emb, W2t, b2t, a_att, a_out, att1_b,
        att2_W, att2_b, user_com, Wb, out);
}

// Round 5
// 961.328 us; speedup vs baseline: 1.5319x; 1.2286x over previous
//
#include <hip/hip_runtime.h>
#include <math.h>

#define L_  50
#define T_  100
#define D_  128
#define NEG_INF_ -9000000000000000.0f

using bf16x8 = __attribute__((ext_vector_type(8))) short;
using f32x4 = __attribute__((ext_vector_type(4))) float;

__device__ __forceinline__ float wred_sum(float v) {
#pragma unroll
    for (int o = 32; o > 0; o >>= 1) v += __shfl_xor(v, o, 64);
    return v;
}
__device__ __forceinline__ float wred_max(float v) {
#pragma unroll
    for (int o = 32; o > 0; o >>= 1) v = fmaxf(v, __shfl_xor(v, o, 64));
    return v;
}
__device__ __forceinline__ float rdlane(float v, int l) {
    return __uint_as_float(__builtin_amdgcn_readlane(__float_as_uint(v), l));
}
__device__ __forceinline__ short f2bf(float f) {  // RNE fp32 -> bf16 bits
    unsigned u = __float_as_uint(f);
    return (short)((u + 0x7fffu + ((u >> 16) & 1u)) >> 16);
}
__device__ __forceinline__ unsigned short f2bfu(float f) {
    unsigned u = __float_as_uint(f);
    return (unsigned short)((u + 0x7fffu + ((u >> 16) & 1u)) >> 16);
}
__device__ __forceinline__ float bf2f(unsigned short u) {
    return __uint_as_float(((unsigned)u) << 16);
}

// ---------------- pre-pass: W -> bf16 MFMA B-frags ---------------------------
// mats 0,1 (W_att, W_out): 9 N-tiles; tile 8 = [W@a1 | W@a2 | 0...] (f1/f2 fold).
// mat 2 (att1_W): 8 N-tiles.
// B-frag of mfma_f32_16x16x32_bf16: lane holds B[k = (lane>>4)*8 + j][n = lane&15].
extern "C" __global__ void __launch_bounds__(256) magnn_preswizzle(
    const float* __restrict__ W0, const float* __restrict__ W1,
    const float* __restrict__ W2, const float* __restrict__ a0,
    const float* __restrict__ a1v, unsigned short* __restrict__ out) {
    const int t = blockIdx.x * 256 + threadIdx.x;  // 0..6655 = 104 groups x 64
    const int gid = t >> 6, lane = t & 63;
    if (gid >= 104) return;
    int mat, kt, nt;
    size_t base;
    if (gid < 72) {
        mat = gid / 36;
        const int rem = gid % 36;
        kt = rem / 9;
        nt = rem % 9;
        base = (size_t)mat * 18432 + (size_t)(((kt * 9 + nt) * 64 + lane) << 3);
    } else {
        mat = 2;
        const int rem = gid - 72;
        kt = rem >> 3;
        nt = rem & 7;
        base = 36864 + (size_t)(((kt * 8 + nt) * 64 + lane) << 3);
    }
    const float* Ws = (mat == 0) ? W0 : (mat == 1) ? W1 : W2;
    const int n = lane & 15;
    const int k0 = kt * 32 + (lane >> 4) * 8;
    bf16x8 v;
    if (nt < 8) {
        const int col = nt * 16 + n;
#pragma unroll
        for (int j = 0; j < 8; ++j) v[j] = f2bf(Ws[(size_t)(k0 + j) * 128 + col]);
    } else {
        if (n < 2) {  // col 128 -> W@a1, col 129 -> W@a2
            const float* av = ((mat == 0) ? a0 : a1v) + n * 128;
#pragma unroll
            for (int j = 0; j < 8; ++j) {
                float s = 0.f;
                const float* wr = Ws + (size_t)(k0 + j) * 128;
                for (int g = 0; g < 128; ++g) s = fmaf(wr[g], av[g], s);
                v[j] = f2bf(s);
            }
        } else {
#pragma unroll
            for (int j = 0; j < 8; ++j) v[j] = 0;
        }
    }
    *(bf16x8*)(out + base) = v;
}

// ---------------- MFMA gemm: 50x128 @ 128x128 (+f1/f2 fold) ------------------
// Wave w owns rows w*16..w*16+15. h stored as bf16 pairs:
// hb[row][c] = (h[row][c], h[row][c+64]) from acc tiles (nt, nt+4).
template <int MODE>  // 0: GAT (9 tiles, raw pairs + f1s/f2s), 1: m1 (8 tiles, tanh+bias)
__device__ __forceinline__ void gemm50_mfma(const unsigned short* __restrict__ Wb,
                                            const float* __restrict__ bias,
                                            const float (&xin)[50][132],
                                            ushort2 (&hb)[50][68],
                                            float* __restrict__ f1s,
                                            float* __restrict__ f2s,
                                            int w, int lane) {
    constexpr int NT = (MODE == 0) ? 9 : 8;
    const int n = lane & 15, quad = lane >> 4;
    const int mrd = w * 16 + n;
    const int mr = (mrd < 50) ? mrd : 49;  // clamp pad rows (results discarded)
    f32x4 acc[NT];
#pragma unroll
    for (int nt = 0; nt < NT; ++nt) acc[nt] = (f32x4){0.f, 0.f, 0.f, 0.f};

#pragma unroll
    for (int kt = 0; kt < 4; ++kt) {
        const float* ap = &xin[mr][kt * 32 + quad * 8];
        const float4 a0 = *(const float4*)ap;
        const float4 a1 = *(const float4*)(ap + 4);
        bf16x8 af;
        af[0] = f2bf(a0.x); af[1] = f2bf(a0.y); af[2] = f2bf(a0.z); af[3] = f2bf(a0.w);
        af[4] = f2bf(a1.x); af[5] = f2bf(a1.y); af[6] = f2bf(a1.z); af[7] = f2bf(a1.w);
        const unsigned short* bp = Wb + (((kt * NT) * 64 + lane) << 3);
#pragma unroll
        for (int nt = 0; nt < NT; ++nt) {
            const bf16x8 bfr = *(const bf16x8*)(bp + (nt << 9));  // (nt*64)*8
            acc[nt] = __builtin_amdgcn_mfma_f32_16x16x32_bf16(af, bfr, acc[nt], 0, 0, 0);
        }
    }
    // C/D: col = lane&15, row(tile) = quad*4 + reg
    const int rbase = w * 16 + quad * 4;
#pragma unroll
    for (int nt = 0; nt < 4; ++nt) {
        const int col = nt * 16 + n;
        const float bl = (MODE == 1) ? bias[col] : 0.f;
        const float bh = (MODE == 1) ? bias[col + 64] : 0.f;
#pragma unroll
        for (int reg = 0; reg < 4; ++reg) {
            const int row = rbase + reg;
            if (row < 50) {
                ushort2 p;
                if (MODE == 1) {
                    p.x = f2bfu(tanhf(acc[nt][reg] + bl));
                    p.y = f2bfu(tanhf(acc[nt + 4][reg] + bh));
                } else {
                    p.x = f2bfu(acc[nt][reg]);
                    p.y = f2bfu(acc[nt + 4][reg]);
                }
                hb[row][col] = p;
            }
        }
    }
    if (MODE == 0 && n < 2) {
        float* fs = n ? f2s : f1s;
#pragma unroll
        for (int reg = 0; reg < 4; ++reg) {
            const int row = rbase + reg;
            if (row < 50) fs[row] = acc[8][reg];
        }
    }
}

extern "C" __global__ void __launch_bounds__(256, 4) magnn_fused(
    const int* __restrict__ iseq, const int* __restrict__ uids,
    const int* __restrict__ itp, const int* __restrict__ A,
    const float* __restrict__ item_emb, const float* __restrict__ user_emb,
    const float* __restrict__ W2t, const float* __restrict__ b2t,
    const float* __restrict__ att2_W, const float* __restrict__ att2_b,
    const float* __restrict__ user_com, const unsigned short* __restrict__ Wb,
    float* __restrict__ out) {
    // LDS: 26400 (x) + 13600 (hb) + 512 (f-scratch) = 40512 -> alloc 40960
    // -> 4 blocks/CU (163840 = 160 KiB exactly).
    __shared__ __align__(16) float x[50][132];
    __shared__ __align__(16) ushort2 hb[50][68];  // pairs; cols 64..67 = attn float4
    __shared__ float fsc[128];
    float* f1s = fsc;
    float* f2s = fsc + 64;
    // fusion-phase scratch in dead x rows:
    float* cat_lo = &x[0][0];
    float* cat_hi = &x[1][0];
    float* fpart = &x[2][0];
    float* vvec = &x[3][0];

    const int tid = threadIdx.x;
    const int b = blockIdx.x;
    const int w = tid >> 6, lane = tid & 63;

    // ---- gather item embeddings into x ----
    {
        const int* isq = iseq + b * L_;
        for (int i = tid; i < L_ * 32; i += 256) {
            const int l = i >> 5, c4 = (i & 31) << 2;
            const int it = isq[l];
            *(float4*)&x[l][c4] = *(const float4*)&item_emb[(size_t)it * D_ + c4];
        }
    }
    __syncthreads();

    // ---- s[d] = sum_l item_embs[l][d] in a register of thread d<128 ----
    float sval = 0.f;
    if (tid < 128) {
#pragma unroll 5
        for (int l = 0; l < L_; ++l) sval += x[l][tid];
    }

    // ---- 2 GAT layers ----
#pragma unroll 1
    for (int layer = 0; layer < 2; ++layer) {
        const unsigned short* Wl = Wb + (layer ? 18432 : 0);
        gemm50_mfma<0>(Wl, nullptr, x, hb, f1s, f2s, w, lane);
        __syncthreads();
        // masked softmax rows + h' = att @ h, 4 rows per wave
        {
            const int* Ab = A + (size_t)b * (L_ * L_);
            const float f2v = (lane < L_) ? f2s[lane] : 0.f;
            for (int k0 = 0; k0 < 13; k0 += 4) {
                float attv[4];
                int lr[4];
                bool vr[4];
#pragma unroll
                for (int r = 0; r < 4; ++r) {
                    const int k = k0 + r;
                    const int l = w + 4 * k;
                    lr[r] = l;
                    vr[r] = (k < 13) && (l < L_);
                    attv[r] = 0.f;
                    if (vr[r]) {
                        const float f1l = f1s[l];
                        const int adj = (lane < L_) ? Ab[l * L_ + lane] : 0;
                        const float e = tanhf(f1l + f2v);
                        const float val =
                            (lane < L_) ? (adj > 0 ? e : NEG_INF_) : -INFINITY;
                        const float m = wred_max(val);
                        const float p = __expf(val - m);
                        const float s = wred_sum(p);
                        attv[r] = p / s;
                    }
                }
                float ac0[4] = {0.f, 0.f, 0.f, 0.f}, ac1[4] = {0.f, 0.f, 0.f, 0.f};
#pragma unroll
                for (int j = 0; j < L_; ++j) {
                    const ushort2 hp = hb[j][lane];
                    const float h0 = bf2f(hp.x), h1 = bf2f(hp.y);
#pragma unroll
                    for (int r = 0; r < 4; ++r) {
                        const float aj = rdlane(attv[r], j);
                        ac0[r] = fmaf(aj, h0, ac0[r]);
                        ac1[r] = fmaf(aj, h1, ac1[r]);
                    }
                }
#pragma unroll
                for (int r = 0; r < 4; ++r)
                    if (vr[r]) {
                        const float e0 = ac0[r], e1 = ac1[r];
                        x[lr[r]][lane] = e0 > 0.f ? e0 : expm1f(e0);
                        x[lr[r]][lane + 64] = e1 > 0.f ? e1 : expm1f(e1);
                    }
            }
        }
        __syncthreads();
    }

    // ---- m1 = tanh(x @ att1_W + att1_b) -> hb (bf16 pairs) ----
    gemm50_mfma<1>(Wb + 36864, /*bias=*/att2_b - 0 + 0 == 0 ? nullptr : nullptr,
                   x, hb, f1s, f2s, w, lane);  // placeholder, fixed below
    // NOTE: bias passed via att1_b argument — see launch (att2_b slot unused here)
    __syncthreads();

    // ---- m2 = m1 @ att2_W + att2_b; attn = softmax over H=4 -> hb[l][64..67] ----
    {
        const float4 awl = *(const float4*)&att2_W[lane * 4];
        const float4 awh = *(const float4*)&att2_W[(lane + 64) * 4];
        const float bb0 = att2_b[0], bb1 = att2_b[1], bb2 = att2_b[2], bb3 = att2_b[3];
        for (int l = w; l < L_; l += 4) {
            const ushort2 qp = hb[l][lane];
            const float q0 = bf2f(qp.x), q1 = bf2f(qp.y);
            float m0 = wred_sum(fmaf(q0, awl.x, q1 * awh.x)) + bb0;
            float m1 = wred_sum(fmaf(q0, awl.y, q1 * awh.y)) + bb1;
            float m2 = wred_sum(fmaf(q0, awl.z, q1 * awh.z)) + bb2;
            float m3 = wred_sum(fmaf(q0, awl.w, q1 * awh.w)) + bb3;
            const float mx = fmaxf(fmaxf(m0, m1), fmaxf(m2, m3));
            const float e0 = __expf(m0 - mx), e1 = __expf(m1 - mx);
            const float e2 = __expf(m2 - mx), e3 = __expf(m3 - mx);
            const float inv = 1.f / (e0 + e1 + e2 + e3);
            if (lane == 0)
                *(float4*)&hb[l][64] =
                    make_float4(e0 * inv, e1 * inv, e2 * inv, e3 * inv);
        }
    }
    __syncthreads();

    // ---- matrix_z -> cat_lo; user_emb -> cat_hi (x rows 0/1 after barrier) ----
    float zval = 0.f;
    if (tid < 128) {
        const int d = tid;
        float z0 = 0.f, z1 = 0.f, z2 = 0.f, z3 = 0.f;
        for (int l = 0; l < L_; ++l) {
            const float xv = x[l][d];
            const float4 at = *(const float4*)&hb[l][64];
            z0 = fmaf(xv, at.x, z0);
            z1 = fmaf(xv, at.y, z1);
            z2 = fmaf(xv, at.z, z2);
            z3 = fmaf(xv, at.w, z3);
        }
        zval = 0.25f * (tanhf(z0) + tanhf(z1) + tanhf(z2) + tanhf(z3));
    } else {
        zval = user_emb[(size_t)uids[b] * D_ + (tid - 128)];
    }
    __syncthreads();  // all x reads done before overwriting rows 0/1
    if (tid < 128) cat_lo[tid] = zval;
    else cat_hi[tid - 128] = zval;
    __syncthreads();

    // ---- fusion = cat @ user_com; v = fusion + s ----
    {
        const int g = tid & 127, hf = tid >> 7;
        const float* cc = hf ? cat_hi : cat_lo;
        const float* ucb = user_com + hf * 128 * 128 + g;
        float acc = 0.f;
#pragma unroll 4
        for (int k = 0; k < 128; ++k) acc = fmaf(cc[k], ucb[(size_t)k * 128], acc);
        if (hf) fpart[g] = acc;
        __syncthreads();
        if (!hf) vvec[g] = acc + fpart[g] + sval;
    }
    __syncthreads();

    // ---- out[b,t] = w2[t]·v + b2[t], 2 reductions in flight ----
    {
        const float vl = vvec[lane], vh = vvec[lane + 64];
        const int* itpb = itp + b * T_;
        for (int t0 = w; t0 < T_; t0 += 8) {
            const int ta = t0, tb = t0 + 4;
            const int ia = itpb[ta];
            const float* wa = W2t + (size_t)ia * D_;
            float ra = fmaf(wa[lane], vl, wa[lane + 64] * vh);
            float rb = 0.f;
            int ib = 0;
            const bool vb = tb < T_;
            if (vb) {
                ib = itpb[tb];
                const float* wbp = W2t + (size_t)ib * D_;
                rb = fmaf(wbp[lane], vl, wbp[lane + 64] * vh);
            }
            ra = wred_sum(ra);
            rb = wred_sum(rb);
            if (lane == 0) {
                out[b * T_ + ta] = ra + b2t[ia];
                if (vb) out[b * T_ + tb] = rb + b2t[ib];
            }
        }
    }
}

// Fix for m1 bias plumbing: wrapper kernel param carries att1_b separately.
// (magnn_fused's gemm50_mfma<1> call needs att1_b; passed as extra arg.)
extern "C" __global__ void __launch_bounds__(64) magnn_dummy() {}

extern "C" void kernel_launch(void* const* d_in, const int* in_sizes, int n_in,
                              void* d_out, int out_size, void* d_ws, size_t ws_size,
                              hipStream_t stream);

// -- real fused kernel with att1_b (replaces placeholder call above) ----------
// To keep a single definition, magnn_fused above is compiled but NOT launched;
// magnn_fused2 below is the launched kernel.
extern "C" __global__ void __launch_bounds__(256, 4) magnn_fused2(
    const int* __restrict__ iseq, const int* __restrict__ uids,
    const int* __restrict__ itp, const int* __restrict__ A,
    const float* __restrict__ item_emb, const float* __restrict__ user_emb,
    const float* __restrict__ W2t, const float* __restrict__ b2t,
    const float* __restrict__ att1_b, const float* __restrict__ att2_W,
    const float* __restrict__ att2_b, const float* __restrict__ user_com,
    const unsigned short* __restrict__ Wb, float* __restrict__ out) {
    __shared__ __align__(16) float x[50][132];
    __shared__ __align__(16) ushort2 hb[50][68];
    __shared__ float fsc[128];
    float* f1s = fsc;
    float* f2s = fsc + 64;
    float* cat_lo = &x[0][0];
    float* cat_hi = &x[1][0];
    float* fpart = &x[2][0];
    float* vvec = &x[3][0];

    const int tid = threadIdx.x;
    const int b = blockIdx.x;
    const int w = tid >> 6, lane = tid & 63;

    {
        const int* isq = iseq + b * L_;
        for (int i = tid; i < L_ * 32; i += 256) {
            const int l = i >> 5, c4 = (i & 31) << 2;
            const int it = isq[l];
            *(float4*)&x[l][c4] = *(const float4*)&item_emb[(size_t)it * D_ + c4];
        }
    }
    __syncthreads();

    float sval = 0.f;
    if (tid < 128) {
#pragma unroll 5
        for (int l = 0; l < L_; ++l) sval += x[l][tid];
    }

#pragma unroll 1
    for (int layer = 0; layer < 2; ++layer) {
        const unsigned short* Wl = Wb + (layer ? 18432 : 0);
        gemm50_mfma<0>(Wl, nullptr, x, hb, f1s, f2s, w, lane);
        __syncthreads();
        {
            const int* Ab = A + (size_t)b * (L_ * L_);
            const float f2v = (lane < L_) ? f2s[lane] : 0.f;
            for (int k0 = 0; k0 < 13; k0 += 4) {
                float attv[4];
                int lr[4];
                bool vr[4];
#pragma unroll
                for (int r = 0; r < 4; ++r) {
                    const int k = k0 + r;
                    const int l = w + 4 * k;
                    lr[r] = l;
                    vr[r] = (k < 13) && (l < L_);
                    attv[r] = 0.f;
                    if (vr[r]) {
                        const float f1l = f1s[l];
                        const int adj = (lane < L_) ? Ab[l * L_ + lane] : 0;
                        const float e = tanhf(f1l + f2v);
                        const float val =
                            (lane < L_) ? (adj > 0 ? e : NEG_INF_) : -INFINITY;
                        const float m = wred_max(val);
                        const float p = __expf(val - m);
                        const float s = wred_sum(p);
                        attv[r] = p / s;
                    }
                }
                float ac0[4] = {0.f, 0.f, 0.f, 0.f}, ac1[4] = {0.f, 0.f, 0.f, 0.f};
#pragma unroll
                for (int j = 0; j < L_; ++j) {
                    const ushort2 hp = hb[j][lane];
                    const float h0 = bf2f(hp.x), h1 = bf2f(hp.y);
#pragma unroll
                    for (int r = 0; r < 4; ++r) {
                        const float aj = rdlane(attv[r], j);
                        ac0[r] = fmaf(aj, h0, ac0[r]);
                        ac1[r] = fmaf(aj, h1, ac1[r]);
                    }
                }
#pragma unroll
                for (int r = 0; r < 4; ++r)
                    if (vr[r]) {
                        const float e0 = ac0[r], e1 = ac1[r];
                        x[lr[r]][lane] = e0 > 0.f ? e0 : expm1f(e0);
                        x[lr[r]][lane + 64] = e1 > 0.f ? e1 : expm1f(e1);
                    }
            }
        }
        __syncthreads();
    }

    gemm50_mfma<1>(Wb + 36864, att1_b, x, hb, f1s, f2s, w, lane);
    __syncthreads();

    {
        const float4 awl = *(const float4*)&att2_W[lane * 4];
        const float4 awh = *(const float4*)&att2_W[(lane + 64) * 4];
        const float bb0 = att2_b[0], bb1 = att2_b[1], bb2 = att2_b[2], bb3 = att2_b[3];
        for (int l = w; l < L_; l += 4) {
            const ushort2 qp = hb[l][lane];
            const float q0 = bf2f(qp.x), q1 = bf2f(qp.y);
            float m0 = wred_sum(fmaf(q0, awl.x, q1 * awh.x)) + bb0;
            float m1 = wred_sum(fmaf(q0, awl.y, q1 * awh.y)) + bb1;
            float m2 = wred_sum(fmaf(q0, awl.z, q1 * awh.z)) + bb2;
            float m3 = wred_sum(fmaf(q0, awl.w, q1 * awh.w)) + bb3;
            const float mx = fmaxf(fmaxf(m0, m1), fmaxf(m2, m3));
            const float e0 = __expf(m0 - mx), e1 = __expf(m1 - mx);
            const float e2 = __expf(m2 - mx), e3 = __expf(m3 - mx);
            const float inv = 1.f / (e0 + e1 + e2 + e3);
            if (lane == 0)
                *(float4*)&hb[l][64] =
                    make_float4(e0 * inv, e1 * inv, e2 * inv, e3 * inv);
        }
    }
    __syncthreads();

    float zval = 0.f;
    if (tid < 128) {
        const int d = tid;
        float z0 = 0.f, z1 = 0.f, z2 = 0.f, z3 = 0.f;
        for (int l = 0; l < L_; ++l) {
            const float xv = x[l][d];
            const float4 at = *(const float4*)&hb[l][64];
            z0 = fmaf(xv, at.x, z0);
            z1 = fmaf(xv, at.y, z1);
            z2 = fmaf(xv, at.z, z2);
            z3 = fmaf(xv, at.w, z3);
        }
        zval = 0.25f * (tanhf(z0) + tanhf(z1) + tanhf(z2) + tanhf(z3));
    } else {
        zval = user_emb[(size_t)uids[b] * D_ + (tid - 128)];
    }
    __syncthreads();
    if (tid < 128) cat_lo[tid] = zval;
    else cat_hi[tid - 128] = zval;
    __syncthreads();

    {
        const int g = tid & 127, hf = tid >> 7;
        const float* cc = hf ? cat_hi : cat_lo;
        const float* ucb = user_com + hf * 128 * 128 + g;
        float acc = 0.f;
#pragma unroll 4
        for (int k = 0; k < 128; ++k) acc = fmaf(cc[k], ucb[(size_t)k * 128], acc);
        if (hf) fpart[g] = acc;
        __syncthreads();
        if (!hf) vvec[g] = acc + fpart[g] + sval;
    }
    __syncthreads();

    {
        const float vl = vvec[lane], vh = vvec[lane + 64];
        const int* itpb = itp + b * T_;
        for (int t0 = w; t0 < T_; t0 += 8) {
            const int ta = t0, tb = t0 + 4;
            const int ia = itpb[ta];
            const float* wa = W2t + (size_t)ia * D_;
            float ra = fmaf(wa[lane], vl, wa[lane + 64] * vh);
            float rb = 0.f;
            int ib = 0;
            const bool vb = tb < T_;
            if (vb) {
                ib = itpb[tb];
                const float* wbp = W2t + (size_t)ib * D_;
                rb = fmaf(wbp[lane], vl, wbp[lane + 64] * vh);
            }
            ra = wred_sum(ra);
            rb = wred_sum(rb);
            if (lane == 0) {
                out[b * T_ + ta] = ra + b2t[ia];
                if (vb) out[b * T_ + tb] = rb + b2t[ib];
            }
        }
    }
}

extern "C" void kernel_launch(void* const* d_in, const int* in_sizes, int n_in,
                              void* d_out, int out_size, void* d_ws, size_t ws_size,
                              hipStream_t stream) {
    const int* iseq = (const int*)d_in[0];
    const int* uids = (const int*)d_in[1];
    const int* itp = (const int*)d_in[2];
    const int* A = (const int*)d_in[3];
    const float* item_emb = (const float*)d_in[4];
    const float* user_emb = (const float*)d_in[5];
    const float* W2t = (const float*)d_in[6];
    const float* b2t = (const float*)d_in[7];
    const float* W_att = (const float*)d_in[8];
    const float* a_att = (const float*)d_in[9];
    const float* W_out = (const float*)d_in[10];
    const float* a_out = (const float*)d_in[11];
    const float* att1_W = (const float*)d_in[12];
    const float* att1_b = (const float*)d_in[13];
    const float* att2_W = (const float*)d_in[14];
    const float* att2_b = (const float*)d_in[15];
    const float* user_com = (const float*)d_in[16];
    float* out = (float*)d_out;
    unsigned short* Wb = (unsigned short*)d_ws;  // 53248 bf16 = 104 KiB

    magnn_preswizzle<<<dim3(26), dim3(256), 0, stream>>>(W_att, W_out, att1_W,
                                                         a_att, a_out, Wb);

    const int B = in_sizes[1];  // user_ids is (B,)
    magnn_fused2<<<dim3(B), dim3(256), 0, stream>>>(
        iseq, uids, itp, A, item_emb, user_emb, W2t, b2t, att1_b, att2_W,
        att2_b, user_com, Wb, out);
}

// Round 6
// 547.049 us; speedup vs baseline: 2.6921x; 1.7573x over previous
//
#include <hip/hip_runtime.h>
#include <math.h>

#define L_  50
#define T_  100
#define NEG_INF_ -9000000000000000.0f

using bf16x8 = __attribute__((ext_vector_type(8))) short;
using f32x4 = __attribute__((ext_vector_type(4))) float;

__device__ __forceinline__ float wred_sum(float v) {
#pragma unroll
    for (int o = 32; o > 0; o >>= 1) v += __shfl_xor(v, o, 64);
    return v;
}
__device__ __forceinline__ float wred_max(float v) {
#pragma unroll
    for (int o = 32; o > 0; o >>= 1) v = fmaxf(v, __shfl_xor(v, o, 64));
    return v;
}
__device__ __forceinline__ short f2bf(float f) {  // RNE fp32 -> bf16 bits
    unsigned u = __float_as_uint(f);
    return (short)((u + 0x7fffu + ((u >> 16) & 1u)) >> 16);
}
__device__ __forceinline__ unsigned short f2bfu(float f) {
    unsigned u = __float_as_uint(f);
    return (unsigned short)((u + 0x7fffu + ((u >> 16) & 1u)) >> 16);
}
__device__ __forceinline__ float bf2f(unsigned short u) {
    return __uint_as_float(((unsigned)u) << 16);
}
// tanh via exp+rcp: ~7 instr, |rel err| ~1e-7 (vs ~20-instr libm tanhf)
__device__ __forceinline__ float tanh_fast(float x) {
    const float cx = fminf(fmaxf(x, -15.f), 15.f);
    const float t = __expf(2.f * cx);
    return (t - 1.f) * __builtin_amdgcn_rcpf(t + 1.f);
}

// ---------------- pre-pass: W -> bf16 MFMA B-frags ---------------------------
// mats 0,1 (W_att, W_out): 9 N-tiles; tile 8 = [W@a1 | W@a2 | 0...] (f1/f2 fold).
// mat 2 (att1_W): 8 N-tiles.
// B-frag of mfma_f32_16x16x32_bf16: lane holds B[k = (lane>>4)*8 + j][n = lane&15].
extern "C" __global__ void __launch_bounds__(256) magnn_preswizzle(
    const float* __restrict__ W0, const float* __restrict__ W1,
    const float* __restrict__ W2, const float* __restrict__ a0,
    const float* __restrict__ a1v, unsigned short* __restrict__ out) {
    const int t = blockIdx.x * 256 + threadIdx.x;  // 104 groups x 64 lanes
    const int gid = t >> 6, lane = t & 63;
    if (gid >= 104) return;
    int mat, kt, nt;
    size_t base;
    if (gid < 72) {
        mat = gid / 36;
        const int rem = gid % 36;
        kt = rem / 9;
        nt = rem % 9;
        base = (size_t)mat * 18432 + (size_t)(((kt * 9 + nt) * 64 + lane) << 3);
    } else {
        mat = 2;
        const int rem = gid - 72;
        kt = rem >> 3;
        nt = rem & 7;
        base = 36864 + (size_t)(((kt * 8 + nt) * 64 + lane) << 3);
    }
    const float* Ws = (mat == 0) ? W0 : (mat == 1) ? W1 : W2;
    const int n = lane & 15;
    const int k0 = kt * 32 + (lane >> 4) * 8;
    bf16x8 v;
    if (nt < 8) {
        const int col = nt * 16 + n;
#pragma unroll
        for (int j = 0; j < 8; ++j) v[j] = f2bf(Ws[(size_t)(k0 + j) * 128 + col]);
    } else {
        if (n < 2) {  // col 128 -> W@a1, col 129 -> W@a2
            const float* av = ((mat == 0) ? a0 : a1v) + n * 128;
#pragma unroll
            for (int j = 0; j < 8; ++j) {
                float s = 0.f;
                const float* wr = Ws + (size_t)(k0 + j) * 128;
                for (int g = 0; g < 128; ++g) s = fmaf(wr[g], av[g], s);
                v[j] = f2bf(s);
            }
        } else {
#pragma unroll
            for (int j = 0; j < 8; ++j) v[j] = 0;
        }
    }
    *(bf16x8*)(out + base) = v;
}

// ---------------- MFMA gemm: ht^T = op( xb(50x128 bf16) @ W ) ----------------
// Wave w owns output rows w*16..w*16+15 (rows>=50 computed from clamped row 49,
// stored as finite junk into ht rows 50..63 -- harmless, multiplied by P=0).
// ht layout: ht[col][row] (col-major) so P@h B-frags are contiguous.
template <int MODE>  // 0: GAT (9 tiles, raw + f1s/f2s fold), 1: m1 (8 tiles, tanh+bias)
__device__ __forceinline__ void gemm50_mfma(
    const unsigned short* __restrict__ Wb, const float* __restrict__ bias,
    const unsigned short (&xb)[50][136], unsigned short (&ht)[128][72],
    float* __restrict__ f1s, float* __restrict__ f2s, int w, int lane) {
    constexpr int NT = (MODE == 0) ? 9 : 8;
    const int n = lane & 15, quad = lane >> 4;
    const int mrd = w * 16 + n;
    const int mr = (mrd < 50) ? mrd : 49;
    f32x4 acc[NT];
#pragma unroll
    for (int nt = 0; nt < NT; ++nt) acc[nt] = (f32x4){0.f, 0.f, 0.f, 0.f};

#pragma unroll
    for (int kt = 0; kt < 4; ++kt) {
        const bf16x8 af = *(const bf16x8*)&xb[mr][kt * 32 + quad * 8];
        const unsigned short* bp = Wb + (((kt * NT) * 64 + lane) << 3);
#pragma unroll
        for (int nt = 0; nt < NT; ++nt) {
            const bf16x8 bfr = *(const bf16x8*)(bp + (nt << 9));
            acc[nt] = __builtin_amdgcn_mfma_f32_16x16x32_bf16(af, bfr, acc[nt], 0, 0, 0);
        }
    }
    // C/D: col = lane&15 (+16*nt), row = w*16 + quad*4 + reg -> ht[col][row]
    const int rbase = w * 16 + quad * 4;
#pragma unroll
    for (int nt = 0; nt < 8; ++nt) {
        const int col = nt * 16 + n;
        const float bv = (MODE == 1) ? bias[col] : 0.f;
        ushort4 pk;
        if (MODE == 1) {
            pk.x = f2bfu(tanh_fast(acc[nt][0] + bv));
            pk.y = f2bfu(tanh_fast(acc[nt][1] + bv));
            pk.z = f2bfu(tanh_fast(acc[nt][2] + bv));
            pk.w = f2bfu(tanh_fast(acc[nt][3] + bv));
        } else {
            pk.x = f2bfu(acc[nt][0]);
            pk.y = f2bfu(acc[nt][1]);
            pk.z = f2bfu(acc[nt][2]);
            pk.w = f2bfu(acc[nt][3]);
        }
        *(ushort4*)&ht[col][rbase] = pk;  // 8B aligned (144B row stride)
    }
    if (MODE == 0 && n < 2) {
        float* fs = n ? f2s : f1s;  // fsc[128]: junk rows 50..63 land in-bounds
#pragma unroll
        for (int reg = 0; reg < 4; ++reg) fs[rbase + reg] = acc[8][reg];
    }
}

extern "C" __global__ void __launch_bounds__(256, 4) magnn_fused(
    const int* __restrict__ iseq, const int* __restrict__ uids,
    const int* __restrict__ itp, const int* __restrict__ A,
    const float* __restrict__ item_emb, const float* __restrict__ user_emb,
    const float* __restrict__ W2t, const float* __restrict__ b2t,
    const float* __restrict__ att1_b, const float* __restrict__ att2_W,
    const float* __restrict__ att2_b, const float* __restrict__ user_com,
    const unsigned short* __restrict__ Wb, float* __restrict__ out) {
    // LDS: xb 13600 + ht 18432 + Pb 7200 + fsc 512 = 39744 B -> 4 blocks/CU.
    // Strides 136/72 ushorts (272/144 B): 16B-aligned b128 frags, <=2-way banks.
    __shared__ __align__(16) unsigned short xb[50][136];  // x, bf16 row-major
    __shared__ __align__(16) unsigned short ht[128][72];  // h^T, bf16 col-major
    __shared__ __align__(16) unsigned short Pb[50][72];   // P (attn), bf16
    __shared__ __align__(16) float fsc[128];
    float* f1s = fsc;
    float* f2s = fsc + 64;
    float* S = (float*)&Pb[0][0];  // Pb dead after GAT layers:
    float* attn4 = S;              // [200] 50 x float4
    float* cat = S + 256;          // [256]
    float* fpart = S + 512;        // [128]
    float* vvec = S + 640;         // [128]

    const int tid = threadIdx.x;
    const int b = blockIdx.x;
    const int w = tid >> 6, lane = tid & 63;
    const int n16 = lane & 15, quad = lane >> 4;

    // ---- gather item embeddings -> xb (bf16); sval exact fp32 from global ----
    const int* isq = iseq + b * L_;
    for (int i = tid; i < L_ * 32; i += 256) {
        const int l = i >> 5, c4 = (i & 31) << 2;
        const float4 v = *(const float4*)&item_emb[(size_t)isq[l] * 128 + c4];
        ushort4 pk;
        pk.x = f2bfu(v.x); pk.y = f2bfu(v.y); pk.z = f2bfu(v.z); pk.w = f2bfu(v.w);
        *(ushort4*)&xb[l][c4] = pk;
    }
    float sval = 0.f;
    if (tid < 128) {
#pragma unroll 5
        for (int l = 0; l < L_; ++l)
            sval += item_emb[(size_t)isq[l] * 128 + tid];  // L1/L2-hot re-read
    }
    __syncthreads();

    // ---- 2 GAT layers ----
#pragma unroll 1
    for (int layer = 0; layer < 2; ++layer) {
        gemm50_mfma<0>(Wb + layer * 18432, nullptr, xb, ht, f1s, f2s, w, lane);
        __syncthreads();
        // masked softmax -> Pb rows (lanes>=50 write exact 0)
        {
            const int* Ab = A + (size_t)b * (L_ * L_);
            const float f2v = (lane < L_) ? f2s[lane] : 0.f;
            for (int k = 0; k < 13; ++k) {
                const int l = w + 4 * k;
                if (l < L_) {
                    const float f1l = f1s[l];
                    const int adj = (lane < L_) ? Ab[l * L_ + lane] : 0;
                    const float e = tanh_fast(f1l + f2v);
                    const float val =
                        (lane < L_) ? (adj > 0 ? e : NEG_INF_) : -INFINITY;
                    const float m = wred_max(val);
                    const float p = __expf(val - m);
                    const float s = wred_sum(p);
                    Pb[l][lane] = f2bfu(p * __builtin_amdgcn_rcpf(s));
                }
            }
        }
        __syncthreads();
        // h' = P @ h via MFMA (A=P rows, B=ht cols); elu -> xb
        {
            const int pm = w * 16 + n16;
            const int pmc = (pm < 50) ? pm : 49;
            const bf16x8 pa0 = *(const bf16x8*)&Pb[pmc][quad * 8];
            const bf16x8 pa1 = *(const bf16x8*)&Pb[pmc][32 + quad * 8];
            f32x4 oacc[8];
#pragma unroll
            for (int nt = 0; nt < 8; ++nt) oacc[nt] = (f32x4){0.f, 0.f, 0.f, 0.f};
#pragma unroll
            for (int nt = 0; nt < 8; ++nt) {
                const bf16x8 h0 = *(const bf16x8*)&ht[nt * 16 + n16][quad * 8];
                oacc[nt] = __builtin_amdgcn_mfma_f32_16x16x32_bf16(pa0, h0, oacc[nt], 0, 0, 0);
            }
#pragma unroll
            for (int nt = 0; nt < 8; ++nt) {
                const bf16x8 h1 = *(const bf16x8*)&ht[nt * 16 + n16][32 + quad * 8];
                oacc[nt] = __builtin_amdgcn_mfma_f32_16x16x32_bf16(pa1, h1, oacc[nt], 0, 0, 0);
            }
            const int rb = w * 16 + quad * 4;
#pragma unroll
            for (int nt = 0; nt < 8; ++nt) {
#pragma unroll
                for (int reg = 0; reg < 4; ++reg) {
                    const int row = rb + reg;
                    if (row < L_) {
                        float e = oacc[nt][reg];
                        e = (e > 0.f) ? e : (__expf(e) - 1.f);
                        xb[row][nt * 16 + n16] = f2bfu(e);
                    }
                }
            }
        }
        __syncthreads();
    }

    // ---- m1 = tanh(x @ att1_W + att1_b) -> ht (bf16, col-major) ----
    gemm50_mfma<1>(Wb + 36864, att1_b, xb, ht, f1s, f2s, w, lane);
    __syncthreads();

    // ---- m2 = m1 @ att2_W + att2_b; softmax over H=4 -> attn4 ----
    {
        const float4 awl = *(const float4*)&att2_W[lane * 4];
        const float4 awh = *(const float4*)&att2_W[(lane + 64) * 4];
        const float bb0 = att2_b[0], bb1 = att2_b[1], bb2 = att2_b[2], bb3 = att2_b[3];
        for (int l = w; l < L_; l += 4) {
            const float q0 = bf2f(ht[lane][l]), q1 = bf2f(ht[lane + 64][l]);
            float m0 = wred_sum(fmaf(q0, awl.x, q1 * awh.x)) + bb0;
            float m1 = wred_sum(fmaf(q0, awl.y, q1 * awh.y)) + bb1;
            float m2 = wred_sum(fmaf(q0, awl.z, q1 * awh.z)) + bb2;
            float m3 = wred_sum(fmaf(q0, awl.w, q1 * awh.w)) + bb3;
            const float mx = fmaxf(fmaxf(m0, m1), fmaxf(m2, m3));
            const float e0 = __expf(m0 - mx), e1 = __expf(m1 - mx);
            const float e2 = __expf(m2 - mx), e3 = __expf(m3 - mx);
            const float inv = 1.f / (e0 + e1 + e2 + e3);
            if (lane == 0)
                *(float4*)&attn4[l * 4] =
                    make_float4(e0 * inv, e1 * inv, e2 * inv, e3 * inv);
        }
    }
    __syncthreads();

    // ---- matrix_z -> cat[0:128]; user_emb -> cat[128:256] (disjoint from attn4)
    if (tid < 128) {
        const int d = tid;
        float z0 = 0.f, z1 = 0.f, z2 = 0.f, z3 = 0.f;
        for (int l = 0; l < L_; ++l) {
            const float xv = bf2f(xb[l][d]);
            const float4 at = *(const float4*)&attn4[l * 4];  // broadcast
            z0 = fmaf(xv, at.x, z0);
            z1 = fmaf(xv, at.y, z1);
            z2 = fmaf(xv, at.z, z2);
            z3 = fmaf(xv, at.w, z3);
        }
        cat[d] = 0.25f * (tanh_fast(z0) + tanh_fast(z1) +
                          tanh_fast(z2) + tanh_fast(z3));
    } else {
        cat[tid] = user_emb[(size_t)uids[b] * 128 + (tid - 128)];
    }
    __syncthreads();

    // ---- fusion = cat @ user_com; v = fusion + s ----
    {
        const int g = tid & 127, hf = tid >> 7;
        const float* ucb = user_com + hf * 128 * 128 + g;
        const float* cc = cat + hf * 128;
        float acc = 0.f;
#pragma unroll 4
        for (int k = 0; k < 128; ++k) acc = fmaf(cc[k], ucb[(size_t)k * 128], acc);
        if (hf) fpart[g] = acc;
        __syncthreads();
        if (!hf) vvec[g] = acc + fpart[g] + sval;
    }
    __syncthreads();

    // ---- out[b,t] = w2[t]·v + b2[t], 2 reductions in flight ----
    {
        const float vl = vvec[lane], vh = vvec[lane + 64];
        const int* itpb = itp + b * T_;
        for (int t0 = w; t0 < T_; t0 += 8) {
            const int ta = t0, tb = t0 + 4;
            const int ia = itpb[ta];
            const float* wa = W2t + (size_t)ia * 128;
            float ra = fmaf(wa[lane], vl, wa[lane + 64] * vh);
            float rb = 0.f;
            int ib = 0;
            const bool vb = tb < T_;
            if (vb) {
                ib = itpb[tb];
                const float* wbp = W2t + (size_t)ib * 128;
                rb = fmaf(wbp[lane], vl, wbp[lane + 64] * vh);
            }
            ra = wred_sum(ra);
            rb = wred_sum(rb);
            if (lane == 0) {
                out[b * T_ + ta] = ra + b2t[ia];
                if (vb) out[b * T_ + tb] = rb + b2t[ib];
            }
        }
    }
}

extern "C" void kernel_launch(void* const* d_in, const int* in_sizes, int n_in,
                              void* d_out, int out_size, void* d_ws, size_t ws_size,
                              hipStream_t stream) {
    const int* iseq = (const int*)d_in[0];
    const int* uids = (const int*)d_in[1];
    const int* itp = (const int*)d_in[2];
    const int* A = (const int*)d_in[3];
    const float* item_emb = (const float*)d_in[4];
    const float* user_emb = (const float*)d_in[5];
    const float* W2t = (const float*)d_in[6];
    const float* b2t = (const float*)d_in[7];
    const float* W_att = (const float*)d_in[8];
    const float* a_att = (const float*)d_in[9];
    const float* W_out = (const float*)d_in[10];
    const float* a_out = (const float*)d_in[11];
    const float* att1_W = (const float*)d_in[12];
    const float* att1_b = (const float*)d_in[13];
    const float* att2_W = (const float*)d_in[14];
    const float* att2_b = (const float*)d_in[15];
    const float* user_com = (const float*)d_in[16];
    float* out = (float*)d_out;
    unsigned short* Wb = (unsigned short*)d_ws;  // 53248 bf16 = 104 KiB

    magnn_preswizzle<<<dim3(26), dim3(256), 0, stream>>>(W_att, W_out, att1_W,
                                                         a_att, a_out, Wb);

    const int B = in_sizes[1];  // user_ids is (B,)
    magnn_fused<<<dim3(B), dim3(256), 0, stream>>>(
        iseq, uids, itp, A, item_emb, user_emb, W2t, b2t, att1_b, att2_W,
        att2_b, user_com, Wb, out);
}